// Round 1
// baseline (1478.809 us; speedup 1.0000x reference)
//
#include <hip/hip_runtime.h>
#include <math.h>

#define EPS 1e-5f

// ---------------------------------------------------------------------------
// Generic fp32 GEMM: O[M][128] = A[M][K] @ W[128][K]^T (+bias) (+relu)
// 64 rows/block, 128 cols, KC=32, 256 threads, 4x8 register tile/thread.
// LDS stride 36 floats: keeps 16B alignment for float4, <=2-way bank alias.
// ---------------------------------------------------------------------------
template <bool RELU, bool BIAS>
__global__ __launch_bounds__(256) void gemm_kernel(
    const float* __restrict__ A, int lda,
    const float* __restrict__ W,          // [128][K] row-major
    const float* __restrict__ bias,       // [128] or null
    float* __restrict__ O, int ldo, int M, int K) {
  __shared__ float As[64][36];
  __shared__ float Ws[128][36];
  const int t = threadIdx.x;
  const int ty = t >> 4;      // 0..15 -> row group
  const int tx = t & 15;      // 0..15 -> col group
  const int row0 = blockIdx.x * 64;

  float acc[4][8];
#pragma unroll
  for (int r = 0; r < 4; ++r)
#pragma unroll
    for (int c = 0; c < 8; ++c) acc[r][c] = 0.f;

  const int ar = t >> 2;            // 0..63
  const int ac = (t & 3) * 8;       // 0,8,16,24
  const int wr = t >> 1;            // 0..127
  const int wc = (t & 1) * 16;      // 0,16

  for (int k0 = 0; k0 < K; k0 += 32) {
    // stage A tile 64x32
    {
      int grow = row0 + ar;
      float4 v0 = make_float4(0.f, 0.f, 0.f, 0.f), v1 = v0;
      if (grow < M) {
        const float* p = A + (size_t)grow * lda + k0 + ac;
        v0 = *(const float4*)p;
        v1 = *(const float4*)(p + 4);
      }
      *(float4*)&As[ar][ac] = v0;
      *(float4*)&As[ar][ac + 4] = v1;
    }
    // stage W tile 128x32
    {
      const float* p = W + (size_t)wr * K + k0 + wc;
      float4 w0 = *(const float4*)(p + 0);
      float4 w1 = *(const float4*)(p + 4);
      float4 w2 = *(const float4*)(p + 8);
      float4 w3 = *(const float4*)(p + 12);
      *(float4*)&Ws[wr][wc + 0] = w0;
      *(float4*)&Ws[wr][wc + 4] = w1;
      *(float4*)&Ws[wr][wc + 8] = w2;
      *(float4*)&Ws[wr][wc + 12] = w3;
    }
    __syncthreads();

#pragma unroll
    for (int kk = 0; kk < 32; kk += 4) {
      float4 a4[4], b4[8];
#pragma unroll
      for (int r = 0; r < 4; ++r) a4[r] = *(const float4*)&As[ty + r * 16][kk];
#pragma unroll
      for (int c = 0; c < 8; ++c) b4[c] = *(const float4*)&Ws[tx + c * 16][kk];
#pragma unroll
      for (int r = 0; r < 4; ++r)
#pragma unroll
        for (int c = 0; c < 8; ++c) {
          acc[r][c] = fmaf(a4[r].x, b4[c].x, acc[r][c]);
          acc[r][c] = fmaf(a4[r].y, b4[c].y, acc[r][c]);
          acc[r][c] = fmaf(a4[r].z, b4[c].z, acc[r][c]);
          acc[r][c] = fmaf(a4[r].w, b4[c].w, acc[r][c]);
        }
    }
    __syncthreads();
  }

#pragma unroll
  for (int r = 0; r < 4; ++r) {
    int grow = row0 + ty + r * 16;
    if (grow >= M) continue;
#pragma unroll
    for (int c = 0; c < 8; ++c) {
      int col = tx + c * 16;
      float v = acc[r][c];
      if (BIAS) v += bias[col];
      if (RELU) v = v > 0.f ? v : 0.f;
      O[(size_t)grow * ldo + col] = v;
    }
  }
}

// ---------------------------------------------------------------------------
// scores[i] = dot(h[i,:], Wsc) + bsc   (one wave per node)
// ---------------------------------------------------------------------------
__global__ __launch_bounds__(256) void score_kernel(
    const float* __restrict__ h, const float* __restrict__ Wsc,
    const float* __restrict__ bsc, float* __restrict__ scores, int M) {
  int wid = threadIdx.x >> 6, lane = threadIdx.x & 63;
  int i = blockIdx.x * 4 + wid;
  if (i >= M) return;
  float acc = h[(size_t)i * 128 + lane] * Wsc[lane] +
              h[(size_t)i * 128 + 64 + lane] * Wsc[64 + lane];
#pragma unroll
  for (int off = 32; off >= 1; off >>= 1) acc += __shfl_xor(acc, off, 64);
  if (lane == 0) scores[i] = acc + bsc[0];
}

// ---------------------------------------------------------------------------
// CSR build: histogram -> scan -> scatter (counting sort by dst)
// ---------------------------------------------------------------------------
__global__ void hist_kernel(const int* __restrict__ dst, int* __restrict__ counts, int E) {
  int e = blockIdx.x * 256 + threadIdx.x;
  if (e < E) atomicAdd(&counts[dst[e]], 1);
}

__global__ __launch_bounds__(256) void scan1_kernel(
    const int* __restrict__ c, int* __restrict__ ex, int* __restrict__ partials, int n) {
  __shared__ int sd[256];
  int t = threadIdx.x, b = blockIdx.x;
  int base = b * 1024 + t * 4;
  int v0 = (base + 0 < n) ? c[base + 0] : 0;
  int v1 = (base + 1 < n) ? c[base + 1] : 0;
  int v2 = (base + 2 < n) ? c[base + 2] : 0;
  int v3 = (base + 3 < n) ? c[base + 3] : 0;
  int tot = v0 + v1 + v2 + v3;
  sd[t] = tot;
  __syncthreads();
  for (int off = 1; off < 256; off <<= 1) {
    int x = (t >= off) ? sd[t - off] : 0;
    __syncthreads();
    sd[t] += x;
    __syncthreads();
  }
  int p = sd[t] - tot;  // exclusive
  if (base + 0 < n) ex[base + 0] = p;
  if (base + 1 < n) ex[base + 1] = p + v0;
  if (base + 2 < n) ex[base + 2] = p + v0 + v1;
  if (base + 3 < n) ex[base + 3] = p + v0 + v1 + v2;
  if (t == 255) partials[b] = sd[255];
}

__global__ __launch_bounds__(256) void scan2_kernel(int* __restrict__ partials, int nb) {
  __shared__ int sd[256];
  int t = threadIdx.x;
  int v = (t < nb) ? partials[t] : 0;
  sd[t] = v;
  __syncthreads();
  for (int off = 1; off < 256; off <<= 1) {
    int x = (t >= off) ? sd[t - off] : 0;
    __syncthreads();
    sd[t] += x;
    __syncthreads();
  }
  if (t < nb) partials[t] = sd[t] - v;  // exclusive
}

__global__ void scan3_kernel(const int* __restrict__ ex, const int* __restrict__ partials,
                             int* __restrict__ indptr, int n, int E) {
  int i = blockIdx.x * 256 + threadIdx.x;
  if (i < n) indptr[i] = ex[i] + partials[i >> 10];
  if (i == 0) indptr[n] = E;
}

__global__ void scatter_kernel(const int* __restrict__ ei, int* __restrict__ cursor,
                               int* __restrict__ ssrc, int E) {
  int e = blockIdx.x * 256 + threadIdx.x;
  if (e >= E) return;
  int s = ei[e];
  int d = ei[E + e];
  int pos = atomicAdd(&cursor[d], 1);
  ssrc[pos] = s;
}

// ---------------------------------------------------------------------------
// Edge aggregation: per node i, sum over incoming edges (CSR), no atomics.
// Writes aggr_fwd -> zcat[:,128:256], aggr_bwd -> zcat[:,256:384].
// ---------------------------------------------------------------------------
__global__ __launch_bounds__(128) void aggr_kernel(
    const int* __restrict__ indptr, const int* __restrict__ ssrc,
    const float* __restrict__ scores, const float* __restrict__ hf,
    const float* __restrict__ hb, float* __restrict__ zcat) {
  int i = blockIdx.x;
  int d = threadIdx.x;
  int beg = indptr[i], end = indptr[i + 1];
  float si = scores[i];
  float af = 0.f, ab = 0.f;
  for (int e = beg; e < end; ++e) {
    int s = ssrc[e];
    float x = scores[s] - si;
    float al = 1.f / (1.f + expf(-x));
    af += al * hf[(size_t)s * 128 + d];
    ab += (1.f - al) * hb[(size_t)s * 128 + d];
  }
  zcat[(size_t)i * 384 + 128 + d] = af;
  zcat[(size_t)i * 384 + 256 + d] = ab;
}

// ---------------------------------------------------------------------------
// LayerNorm + ReLU + residual (in-place into h). One wave per row.
// ---------------------------------------------------------------------------
__global__ __launch_bounds__(256) void ln_kernel(
    const float* __restrict__ z, const float* __restrict__ gamma,
    const float* __restrict__ beta, float* __restrict__ h, int M) {
  int wid = threadIdx.x >> 6, lane = threadIdx.x & 63;
  int i = blockIdx.x * 4 + wid;
  if (i >= M) return;
  float z0 = z[(size_t)i * 128 + lane];
  float z1 = z[(size_t)i * 128 + 64 + lane];
  float s1 = z0 + z1;
  float s2 = z0 * z0 + z1 * z1;
#pragma unroll
  for (int off = 32; off >= 1; off >>= 1) {
    s1 += __shfl_xor(s1, off, 64);
    s2 += __shfl_xor(s2, off, 64);
  }
  float mu = s1 * (1.f / 128.f);
  float var = s2 * (1.f / 128.f) - mu * mu;
  float rs = rsqrtf(var + EPS);
  float o0 = (z0 - mu) * rs * gamma[lane] + beta[lane];
  float o1 = (z1 - mu) * rs * gamma[64 + lane] + beta[64 + lane];
  o0 = fmaxf(o0, 0.f);
  o1 = fmaxf(o1, 0.f);
  size_t p0 = (size_t)i * 128 + lane;
  size_t p1 = p0 + 64;
  h[p0] = o0 + h[p0];
  h[p1] = o1 + h[p1];
}

// ---------------------------------------------------------------------------
// Global mean pool (batch is sorted)
// ---------------------------------------------------------------------------
__global__ __launch_bounds__(128) void pool_accum_kernel(
    const float* __restrict__ h, const int* __restrict__ batch,
    float* __restrict__ sums, int M) {
  int i0 = blockIdx.x * 128;
  int d = threadIdx.x;
  float acc = 0.f;
  int cur = -1;
  for (int ii = 0; ii < 128; ++ii) {
    int i = i0 + ii;
    if (i >= M) break;
    int g = batch[i];
    if (g != cur) {
      if (cur >= 0) atomicAdd(&sums[cur * 128 + d], acc);
      acc = 0.f;
      cur = g;
    }
    acc += h[(size_t)i * 128 + d];
  }
  if (cur >= 0) atomicAdd(&sums[cur * 128 + d], acc);
}

__global__ void count_kernel(const int* __restrict__ batch, int* __restrict__ cnt, int M) {
  int i = blockIdx.x * 256 + threadIdx.x;
  if (i < M) atomicAdd(&cnt[batch[i]], 1);
}

__global__ void finalize_kernel(const float* __restrict__ sums, const int* __restrict__ cnt,
                                float* __restrict__ out, int G) {
  int idx = blockIdx.x * 256 + threadIdx.x;
  if (idx < G * 128) {
    int g = idx >> 7;
    int c = cnt[g];
    float cf = (float)(c > 0 ? c : 1);
    out[idx] = sums[idx] / cf;
  }
}

// ---------------------------------------------------------------------------
extern "C" void kernel_launch(void* const* d_in, const int* in_sizes, int n_in,
                              void* d_out, int out_size, void* d_ws, size_t ws_size,
                              hipStream_t stream) {
  const float* x      = (const float*)d_in[0];
  const int*   ei     = (const int*)d_in[1];
  const int*   batch  = (const int*)d_in[2];
  const float* Wemb   = (const float*)d_in[3];
  const float* bemb   = (const float*)d_in[4];
  const float* Wscore = (const float*)d_in[5];
  const float* bscore = (const float*)d_in[6];
  const float* Wfwd   = (const float*)d_in[7];
  const float* Wbwd   = (const float*)d_in[8];
  const float* Wself  = (const float*)d_in[9];
  const float* bself  = (const float*)d_in[10];
  const float* Wcomb  = (const float*)d_in[11];
  const float* bcomb  = (const float*)d_in[12];
  const float* gamma  = (const float*)d_in[13];
  const float* beta   = (const float*)d_in[14];

  const int N = in_sizes[0] / 128;
  const int E = in_sizes[1] / 2;
  const int L = in_sizes[5] / 128;
  const int G = out_size / 128;
  float* out = (float*)d_out;

  // workspace carve-up
  char* p = (char*)d_ws;
  auto alloc = [&](size_t bytes) -> char* {
    char* r = p;
    p += (bytes + 255) & ~(size_t)255;
    return r;
  };
  float* h      = (float*)alloc((size_t)N * 128 * 4);
  float* hf     = (float*)alloc((size_t)N * 128 * 4);
  float* hb     = (float*)alloc((size_t)N * 128 * 4);
  float* zcat   = (float*)alloc((size_t)N * 384 * 4);   // [h_self | aggr_f | aggr_b]
  float* z      = (float*)alloc((size_t)N * 128 * 4);
  float* scores = (float*)alloc((size_t)N * 4);
  int* counts   = (int*)alloc((size_t)N * 4);
  int* ex       = (int*)alloc((size_t)N * 4);
  int* partials = (int*)alloc(1024);
  int* indptr   = (int*)alloc((size_t)(N + 1) * 4);
  int* cursor   = (int*)alloc((size_t)N * 4);
  int* ssrc     = (int*)alloc((size_t)E * 4);
  float* sums   = (float*)alloc((size_t)G * 128 * 4);
  int* cnt      = (int*)alloc((size_t)G * 4);

  const int gb = (N + 63) / 64;

  // 1. embedding: h = relu(x @ Wemb^T + bemb)
  gemm_kernel<true, true><<<gb, 256, 0, stream>>>(x, 128, Wemb, bemb, h, 128, N, 128);

  // 2. CSR build (once; edges constant within a call)
  hipMemsetAsync(counts, 0, (size_t)N * 4, stream);
  hist_kernel<<<(E + 255) / 256, 256, 0, stream>>>(ei + E, counts, E);
  int nb = (N + 1023) / 1024;
  scan1_kernel<<<nb, 256, 0, stream>>>(counts, ex, partials, N);
  scan2_kernel<<<1, 256, 0, stream>>>(partials, nb);
  scan3_kernel<<<(N + 255) / 256, 256, 0, stream>>>(ex, partials, indptr, N, E);
  hipMemcpyAsync(cursor, indptr, (size_t)N * 4, hipMemcpyDeviceToDevice, stream);
  scatter_kernel<<<(E + 255) / 256, 256, 0, stream>>>(ei, cursor, ssrc, E);

  // 3. layers
  for (int l = 0; l < L; ++l) {
    const float* Wf = Wfwd + (size_t)l * 128 * 128;
    const float* Wb = Wbwd + (size_t)l * 128 * 128;
    const float* Wsl = Wself + (size_t)l * 128 * 128;
    const float* Wc = Wcomb + (size_t)l * 128 * 384;
    gemm_kernel<false, false><<<gb, 256, 0, stream>>>(h, 128, Wf, nullptr, hf, 128, N, 128);
    gemm_kernel<false, false><<<gb, 256, 0, stream>>>(h, 128, Wb, nullptr, hb, 128, N, 128);
    gemm_kernel<false, true><<<gb, 256, 0, stream>>>(h, 128, Wsl, bself + (size_t)l * 128,
                                                     zcat, 384, N, 128);
    score_kernel<<<(N + 3) / 4, 256, 0, stream>>>(h, Wscore + (size_t)l * 128, bscore + l,
                                                  scores, N);
    aggr_kernel<<<N, 128, 0, stream>>>(indptr, ssrc, scores, hf, hb, zcat);
    gemm_kernel<false, true><<<gb, 256, 0, stream>>>(zcat, 384, Wc, bcomb + (size_t)l * 128,
                                                     z, 128, N, 384);
    ln_kernel<<<(N + 3) / 4, 256, 0, stream>>>(z, gamma + (size_t)l * 128,
                                               beta + (size_t)l * 128, h, N);
  }

  // 4. global mean pool
  hipMemsetAsync(sums, 0, (size_t)G * 128 * 4, stream);
  hipMemsetAsync(cnt, 0, (size_t)G * 4, stream);
  pool_accum_kernel<<<(N + 127) / 128, 128, 0, stream>>>(h, batch, sums, N);
  count_kernel<<<(N + 255) / 256, 256, 0, stream>>>(batch, cnt, N);
  finalize_kernel<<<(G * 128 + 255) / 256, 256, 0, stream>>>(sums, cnt, out, G);
}

// Round 2
// 733.334 us; speedup vs baseline: 2.0166x; 2.0166x over previous
//
#include <hip/hip_runtime.h>
#include <math.h>

#define EPS 1e-5f

typedef __attribute__((ext_vector_type(8))) short short8;
typedef __attribute__((ext_vector_type(4))) float f32x4;

__device__ __forceinline__ float bflo(unsigned u) {
  union { unsigned i; float f; } c; c.i = u << 16; return c.f;
}
__device__ __forceinline__ float bfhi(unsigned u) {
  union { unsigned i; float f; } c; c.i = u & 0xFFFF0000u; return c.f;
}
__device__ __forceinline__ unsigned short f2bf(float f) {
  union { float f; unsigned i; } c; c.f = f;
  unsigned r = c.i + 0x7FFF + ((c.i >> 16) & 1);
  return (unsigned short)(r >> 16);
}

// ---------------------------------------------------------------------------
// bf16 MFMA GEMM: O[M][*] = A[M][K] @ W[Ncols][K]^T (+bias)(+relu)
// Block 256 thr = 4 waves (2x2), tile 128Mx128N, per-wave 64x64, 16x16x32 MFMA.
// Fragments loaded per-lane directly from global (row-major bf16, 16B/lane).
// MODE 0: embed  -> dual out: outF fp32 [M][128] + outB bf16 [M][128], relu
// MODE 1: fused3 -> blockIdx.y==0: bf16 out to outB (zcat, ldo 384, +bias)
//                   blockIdx.y>0 : bf16 out to outB2 (hfb, ldo 256, cols (y-1)*128)
// MODE 2: comb   -> outF fp32 [M][128] (+bias)
// ---------------------------------------------------------------------------
template <int KT, int MODE>
__global__ __launch_bounds__(256) void mfma_gemm(
    const ushort* __restrict__ A, int lda,
    const ushort* __restrict__ W,
    const float* __restrict__ bias,
    float* __restrict__ outF,
    ushort* __restrict__ outB,
    ushort* __restrict__ outB2,
    int M) {
  constexpr int K = KT * 32;
  const int t = threadIdx.x;
  const int lane = t & 63;
  const int w = t >> 6;
  const int wm = w >> 1, wn = w & 1;
  const int m0 = blockIdx.x * 128 + wm * 64;
  const int nb = blockIdx.y;
  const int l15 = lane & 15, l16 = lane >> 4;

  f32x4 acc[4][4];
#pragma unroll
  for (int i = 0; i < 4; ++i)
#pragma unroll
    for (int j = 0; j < 4; ++j) acc[i][j] = (f32x4){0.f, 0.f, 0.f, 0.f};

#pragma unroll
  for (int kk = 0; kk < KT; ++kk) {
    const int ko = kk * 32 + l16 * 8;
    short8 a[4], b[4];
#pragma unroll
    for (int i = 0; i < 4; ++i) {
      int row = m0 + i * 16 + l15;
      if (row >= M) row = M - 1;
      a[i] = *(const short8*)(A + (size_t)row * lda + ko);
    }
#pragma unroll
    for (int j = 0; j < 4; ++j) {
      int col = nb * 128 + wn * 64 + j * 16 + l15;  // row of W
      b[j] = *(const short8*)(W + (size_t)col * K + ko);
    }
#pragma unroll
    for (int i = 0; i < 4; ++i)
#pragma unroll
      for (int j = 0; j < 4; ++j)
        acc[i][j] = __builtin_amdgcn_mfma_f32_16x16x32_bf16(a[i], b[j], acc[i][j], 0, 0, 0);
  }

  // epilogue: C/D layout col=lane&15, row=(lane>>4)*4+reg
#pragma unroll
  for (int i = 0; i < 4; ++i) {
#pragma unroll
    for (int r = 0; r < 4; ++r) {
      int row = m0 + i * 16 + l16 * 4 + r;
      if (row >= M) continue;
#pragma unroll
      for (int j = 0; j < 4; ++j) {
        int colw = wn * 64 + j * 16 + l15;  // 0..127 within n-tile
        float v = acc[i][j][r];
        if (MODE == 0) {
          v += bias[colw];
          v = fmaxf(v, 0.f);
          outF[(size_t)row * 128 + colw] = v;
          outB[(size_t)row * 128 + colw] = f2bf(v);
        } else if (MODE == 2) {
          v += bias[colw];
          outF[(size_t)row * 128 + colw] = v;
        } else {
          if (nb == 0) {
            v += bias[colw];
            outB[(size_t)row * 384 + colw] = f2bf(v);
          } else {
            outB2[(size_t)row * 256 + (nb - 1) * 128 + colw] = f2bf(v);
          }
        }
      }
    }
  }
}

// ---------------------------------------------------------------------------
// fp32 -> bf16 convert (n4 = n/4 float4 groups)
// ---------------------------------------------------------------------------
__global__ void f2b_kernel(const float* __restrict__ in, ushort* __restrict__ out, int n4) {
  int i = blockIdx.x * 256 + threadIdx.x;
  if (i < n4) {
    float4 v = ((const float4*)in)[i];
    ushort4 o;
    o.x = f2bf(v.x); o.y = f2bf(v.y); o.z = f2bf(v.z); o.w = f2bf(v.w);
    ((ushort4*)out)[i] = o;
  }
}

// W3[l] = [Wself | Wfwd | Wbwd] stacked rows, bf16  (49152 elems)
__global__ void build_w3_kernel(const float* __restrict__ Ws, const float* __restrict__ Wf,
                                const float* __restrict__ Wb, ushort* __restrict__ W3) {
  int i = blockIdx.x * 256 + threadIdx.x;
  if (i >= 49152) return;
  float v;
  if (i < 16384) v = Ws[i];
  else if (i < 32768) v = Wf[i - 16384];
  else v = Wb[i - 32768];
  W3[i] = f2bf(v);
}

// ---------------------------------------------------------------------------
// scores[i] = dot(h_bf16[i,:], Wsc) + bsc   (one wave per node)
// ---------------------------------------------------------------------------
__global__ __launch_bounds__(256) void score_kernel(
    const ushort* __restrict__ hb, const float* __restrict__ Wsc,
    const float* __restrict__ bsc, float* __restrict__ scores, int M) {
  int i = blockIdx.x * 4 + (threadIdx.x >> 6);
  if (i >= M) return;
  int lane = threadIdx.x & 63;
  unsigned v = *(const unsigned*)(hb + (size_t)i * 128 + lane * 2);
  float acc = bflo(v) * Wsc[2 * lane] + bfhi(v) * Wsc[2 * lane + 1];
#pragma unroll
  for (int off = 32; off >= 1; off >>= 1) acc += __shfl_xor(acc, off, 64);
  if (lane == 0) scores[i] = acc + bsc[0];
}

// ---------------------------------------------------------------------------
// CSR build: histogram -> scan -> scatter (counting sort by dst)
// ---------------------------------------------------------------------------
__global__ void hist_kernel(const int* __restrict__ dst, int* __restrict__ counts, int E) {
  int e = blockIdx.x * 256 + threadIdx.x;
  if (e < E) atomicAdd(&counts[dst[e]], 1);
}

__global__ __launch_bounds__(256) void scan1_kernel(
    const int* __restrict__ c, int* __restrict__ ex, int* __restrict__ partials, int n) {
  __shared__ int sd[256];
  int t = threadIdx.x, b = blockIdx.x;
  int base = b * 1024 + t * 4;
  int v0 = (base + 0 < n) ? c[base + 0] : 0;
  int v1 = (base + 1 < n) ? c[base + 1] : 0;
  int v2 = (base + 2 < n) ? c[base + 2] : 0;
  int v3 = (base + 3 < n) ? c[base + 3] : 0;
  int tot = v0 + v1 + v2 + v3;
  sd[t] = tot;
  __syncthreads();
  for (int off = 1; off < 256; off <<= 1) {
    int x = (t >= off) ? sd[t - off] : 0;
    __syncthreads();
    sd[t] += x;
    __syncthreads();
  }
  int p = sd[t] - tot;  // exclusive
  if (base + 0 < n) ex[base + 0] = p;
  if (base + 1 < n) ex[base + 1] = p + v0;
  if (base + 2 < n) ex[base + 2] = p + v0 + v1;
  if (base + 3 < n) ex[base + 3] = p + v0 + v1 + v2;
  if (t == 255) partials[b] = sd[255];
}

__global__ __launch_bounds__(256) void scan2_kernel(int* __restrict__ partials, int nb) {
  __shared__ int sd[256];
  int t = threadIdx.x;
  int v = (t < nb) ? partials[t] : 0;
  sd[t] = v;
  __syncthreads();
  for (int off = 1; off < 256; off <<= 1) {
    int x = (t >= off) ? sd[t - off] : 0;
    __syncthreads();
    sd[t] += x;
    __syncthreads();
  }
  if (t < nb) partials[t] = sd[t] - v;  // exclusive
}

__global__ void scan3_kernel(const int* __restrict__ ex, const int* __restrict__ partials,
                             int* __restrict__ indptr, int n, int E) {
  int i = blockIdx.x * 256 + threadIdx.x;
  if (i < n) indptr[i] = ex[i] + partials[i >> 10];
  if (i == 0) indptr[n] = E;
}

__global__ void scatter_kernel(const int* __restrict__ ei, int* __restrict__ cursor,
                               int* __restrict__ ssrc, int E) {
  int e = blockIdx.x * 256 + threadIdx.x;
  if (e >= E) return;
  int s = ei[e];
  int d = ei[E + e];
  int pos = atomicAdd(&cursor[d], 1);
  ssrc[pos] = s;
}

// ---------------------------------------------------------------------------
// Edge aggregation: 1 wave per node, CSR, no atomics, bf16 gather.
// hfb row = [fwd(128) | bwd(128)] bf16 (512B); lane covers 4 dims via uint2.
// Writes aggrF/aggrB into zcat cols 128..383 (= 128 + 4*lane + e).
// ---------------------------------------------------------------------------
__global__ __launch_bounds__(256) void aggr_kernel(
    const int* __restrict__ indptr, const int* __restrict__ ssrc,
    const float* __restrict__ scores, const ushort* __restrict__ hfb,
    ushort* __restrict__ zcat, int Nn) {
  int node = blockIdx.x * 4 + (threadIdx.x >> 6);
  if (node >= Nn) return;
  int lane = threadIdx.x & 63;
  int beg = indptr[node], end = indptr[node + 1];
  float si = scores[node];
  float a0 = 0.f, a1 = 0.f, a2 = 0.f, a3 = 0.f;
  const bool fwd = lane < 32;
  for (int e = beg; e < end; ++e) {
    int s = ssrc[e];
    float al = 1.f / (1.f + __expf(si - scores[s]));  // sigmoid(scores[s]-si)
    float wgt = fwd ? al : 1.f - al;
    uint2 v = *(const uint2*)(hfb + (size_t)s * 256 + lane * 4);
    a0 = fmaf(wgt, bflo(v.x), a0);
    a1 = fmaf(wgt, bfhi(v.x), a1);
    a2 = fmaf(wgt, bflo(v.y), a2);
    a3 = fmaf(wgt, bfhi(v.y), a3);
  }
  ushort4 o;
  o.x = f2bf(a0); o.y = f2bf(a1); o.z = f2bf(a2); o.w = f2bf(a3);
  *(ushort4*)(zcat + (size_t)node * 384 + 128 + lane * 4) = o;
}

// ---------------------------------------------------------------------------
// LayerNorm + ReLU + residual. h (fp32) += ..., also writes bf16 copy.
// ---------------------------------------------------------------------------
__global__ __launch_bounds__(256) void ln_kernel(
    const float* __restrict__ z, const float* __restrict__ gamma,
    const float* __restrict__ beta, float* __restrict__ h,
    ushort* __restrict__ hb, int M) {
  int wid = threadIdx.x >> 6, lane = threadIdx.x & 63;
  int i = blockIdx.x * 4 + wid;
  if (i >= M) return;
  float z0 = z[(size_t)i * 128 + lane];
  float z1 = z[(size_t)i * 128 + 64 + lane];
  float s1 = z0 + z1;
  float s2 = z0 * z0 + z1 * z1;
#pragma unroll
  for (int off = 32; off >= 1; off >>= 1) {
    s1 += __shfl_xor(s1, off, 64);
    s2 += __shfl_xor(s2, off, 64);
  }
  float mu = s1 * (1.f / 128.f);
  float var = s2 * (1.f / 128.f) - mu * mu;
  float rs = rsqrtf(var + EPS);
  float o0 = (z0 - mu) * rs * gamma[lane] + beta[lane];
  float o1 = (z1 - mu) * rs * gamma[64 + lane] + beta[64 + lane];
  o0 = fmaxf(o0, 0.f);
  o1 = fmaxf(o1, 0.f);
  size_t p0 = (size_t)i * 128 + lane;
  size_t p1 = p0 + 64;
  float r0 = o0 + h[p0];
  float r1 = o1 + h[p1];
  h[p0] = r0;
  h[p1] = r1;
  hb[p0] = f2bf(r0);
  hb[p1] = f2bf(r1);
}

// ---------------------------------------------------------------------------
// Global mean pool (batch sorted). Counts via binary search (no atomics).
// ---------------------------------------------------------------------------
__global__ __launch_bounds__(128) void pool_accum_kernel(
    const float* __restrict__ h, const int* __restrict__ batch,
    float* __restrict__ sums, int M) {
  int i0 = blockIdx.x * 128;
  int d = threadIdx.x;
  float acc = 0.f;
  int cur = -1;
  for (int ii = 0; ii < 128; ++ii) {
    int i = i0 + ii;
    if (i >= M) break;
    int g = batch[i];
    if (g != cur) {
      if (cur >= 0) atomicAdd(&sums[cur * 128 + d], acc);
      acc = 0.f;
      cur = g;
    }
    acc += h[(size_t)i * 128 + d];
  }
  if (cur >= 0) atomicAdd(&sums[cur * 128 + d], acc);
}

__global__ void group_count_kernel(const int* __restrict__ batch, int* __restrict__ cnt,
                                   int M, int G) {
  int g = blockIdx.x * 64 + threadIdx.x;
  if (g >= G) return;
  int lo = 0, hi = M;
  while (lo < hi) { int mid = (lo + hi) >> 1; if (batch[mid] < g) lo = mid + 1; else hi = mid; }
  int b0 = lo;
  lo = 0; hi = M;
  while (lo < hi) { int mid = (lo + hi) >> 1; if (batch[mid] < g + 1) lo = mid + 1; else hi = mid; }
  cnt[g] = lo - b0;
}

__global__ void finalize_kernel(const float* __restrict__ sums, const int* __restrict__ cnt,
                                float* __restrict__ out, int G) {
  int idx = blockIdx.x * 256 + threadIdx.x;
  if (idx < G * 128) {
    int g = idx >> 7;
    int c = cnt[g];
    float cf = (float)(c > 0 ? c : 1);
    out[idx] = sums[idx] / cf;
  }
}

// ---------------------------------------------------------------------------
extern "C" void kernel_launch(void* const* d_in, const int* in_sizes, int n_in,
                              void* d_out, int out_size, void* d_ws, size_t ws_size,
                              hipStream_t stream) {
  const float* x      = (const float*)d_in[0];
  const int*   ei     = (const int*)d_in[1];
  const int*   batch  = (const int*)d_in[2];
  const float* Wemb   = (const float*)d_in[3];
  const float* bemb   = (const float*)d_in[4];
  const float* Wscore = (const float*)d_in[5];
  const float* bscore = (const float*)d_in[6];
  const float* Wfwd   = (const float*)d_in[7];
  const float* Wbwd   = (const float*)d_in[8];
  const float* Wself  = (const float*)d_in[9];
  const float* bself  = (const float*)d_in[10];
  const float* Wcomb  = (const float*)d_in[11];
  const float* bcomb  = (const float*)d_in[12];
  const float* gamma  = (const float*)d_in[13];
  const float* beta   = (const float*)d_in[14];

  const int N = in_sizes[0] / 128;
  const int E = in_sizes[1] / 2;
  const int L = in_sizes[5] / 128;
  const int G = out_size / 128;
  float* out = (float*)d_out;

  // workspace carve-up
  char* p = (char*)d_ws;
  auto alloc = [&](size_t bytes) -> char* {
    char* r = p;
    p += (bytes + 255) & ~(size_t)255;
    return r;
  };
  float*  h      = (float*)alloc((size_t)N * 128 * 4);
  ushort* hb16   = (ushort*)alloc((size_t)N * 128 * 2);
  ushort* xb16   = (ushort*)alloc((size_t)N * 128 * 2);
  ushort* hfb    = (ushort*)alloc((size_t)N * 256 * 2);   // [fwd | bwd] bf16
  ushort* zcat   = (ushort*)alloc((size_t)N * 384 * 2);   // [self | aggrF | aggrB] bf16
  float*  z      = (float*)alloc((size_t)N * 128 * 4);
  float*  scores = (float*)alloc((size_t)N * 4);
  ushort* Wemb_b = (ushort*)alloc(16384 * 2);
  ushort* W3_b   = (ushort*)alloc((size_t)L * 49152 * 2);
  ushort* Wc_b   = (ushort*)alloc((size_t)L * 49152 * 2);
  int* counts    = (int*)alloc((size_t)N * 4);
  int* ex        = (int*)alloc((size_t)N * 4);
  int* partials  = (int*)alloc(1024);
  int* indptr    = (int*)alloc((size_t)(N + 1) * 4);
  int* cursor    = (int*)alloc((size_t)N * 4);
  int* ssrc      = (int*)alloc((size_t)E * 4);
  float* sums    = (float*)alloc((size_t)G * 128 * 4);
  int* cnt       = (int*)alloc((size_t)G * 4);

  const int gb = (N + 127) / 128;

  // 0. dtype conversions (once per call)
  f2b_kernel<<<(N * 32 + 255) / 256, 256, 0, stream>>>(x, xb16, N * 32);
  f2b_kernel<<<(4096 + 255) / 256, 256, 0, stream>>>(Wemb, Wemb_b, 4096);
  f2b_kernel<<<(L * 12288 + 255) / 256, 256, 0, stream>>>(Wcomb, Wc_b, L * 12288);
  for (int l = 0; l < L; ++l)
    build_w3_kernel<<<192, 256, 0, stream>>>(Wself + (size_t)l * 16384,
                                             Wfwd + (size_t)l * 16384,
                                             Wbwd + (size_t)l * 16384,
                                             W3_b + (size_t)l * 49152);

  // 1. embedding: h = relu(x @ Wemb^T + bemb), dual fp32 + bf16 out
  mfma_gemm<4, 0><<<dim3(gb, 1), 256, 0, stream>>>(xb16, 128, Wemb_b, bemb, h, hb16,
                                                   nullptr, N);

  // 2. CSR build
  hipMemsetAsync(counts, 0, (size_t)N * 4, stream);
  hist_kernel<<<(E + 255) / 256, 256, 0, stream>>>(ei + E, counts, E);
  int nb = (N + 1023) / 1024;
  scan1_kernel<<<nb, 256, 0, stream>>>(counts, ex, partials, N);
  scan2_kernel<<<1, 256, 0, stream>>>(partials, nb);
  scan3_kernel<<<(N + 255) / 256, 256, 0, stream>>>(ex, partials, indptr, N, E);
  hipMemcpyAsync(cursor, indptr, (size_t)N * 4, hipMemcpyDeviceToDevice, stream);
  scatter_kernel<<<(E + 255) / 256, 256, 0, stream>>>(ei, cursor, ssrc, E);

  // 3. layers
  for (int l = 0; l < L; ++l) {
    // fused [self|fwd|bwd] GEMM: self -> zcat cols 0..127 (+bself), fwd/bwd -> hfb
    mfma_gemm<4, 1><<<dim3(gb, 3), 256, 0, stream>>>(hb16, 128,
                                                     W3_b + (size_t)l * 49152,
                                                     bself + (size_t)l * 128,
                                                     nullptr, zcat, hfb, N);
    score_kernel<<<(N + 3) / 4, 256, 0, stream>>>(hb16, Wscore + (size_t)l * 128,
                                                  bscore + l, scores, N);
    aggr_kernel<<<(N + 3) / 4, 256, 0, stream>>>(indptr, ssrc, scores, hfb, zcat, N);
    mfma_gemm<12, 2><<<dim3(gb, 1), 256, 0, stream>>>(zcat, 384,
                                                      Wc_b + (size_t)l * 49152,
                                                      bcomb + (size_t)l * 128,
                                                      z, nullptr, nullptr, N);
    ln_kernel<<<(N + 3) / 4, 256, 0, stream>>>(z, gamma + (size_t)l * 128,
                                               beta + (size_t)l * 128, h, hb16, N);
  }

  // 4. global mean pool
  hipMemsetAsync(sums, 0, (size_t)G * 128 * 4, stream);
  group_count_kernel<<<(G + 63) / 64, 64, 0, stream>>>(batch, cnt, N, G);
  pool_accum_kernel<<<(N + 127) / 128, 128, 0, stream>>>(h, batch, sums, N);
  finalize_kernel<<<(G * 128 + 255) / 256, 256, 0, stream>>>(sums, cnt, out, G);
}

// Round 3
// 558.764 us; speedup vs baseline: 2.6466x; 1.3124x over previous
//
#include <hip/hip_runtime.h>
#include <math.h>

#define EPS 1e-5f

typedef __attribute__((ext_vector_type(8))) short short8;
typedef __attribute__((ext_vector_type(4))) float f32x4;

__device__ __forceinline__ float bflo(unsigned u) {
  union { unsigned i; float f; } c; c.i = u << 16; return c.f;
}
__device__ __forceinline__ float bfhi(unsigned u) {
  union { unsigned i; float f; } c; c.i = u & 0xFFFF0000u; return c.f;
}
__device__ __forceinline__ unsigned short f2bf(float f) {
  union { float f; unsigned i; } c; c.f = f;
  unsigned r = c.i + 0x7FFF + ((c.i >> 16) & 1);
  return (unsigned short)(r >> 16);
}

// ---------------------------------------------------------------------------
// Embed GEMM: out = relu(A[M][128] @ W[128][128]^T + bias), dual fp32+bf16 out.
// 256 thr = 4 waves 2x2, tile 128x128, per-wave 64x64, mfma 16x16x32 bf16.
// ---------------------------------------------------------------------------
__global__ __launch_bounds__(256) void embed_gemm(
    const ushort* __restrict__ A, const ushort* __restrict__ W,
    const float* __restrict__ bias, float* __restrict__ outF,
    ushort* __restrict__ outB, int M) {
  const int t = threadIdx.x;
  const int lane = t & 63;
  const int w = t >> 6;
  const int wm = w >> 1, wn = w & 1;
  const int m0 = blockIdx.x * 128 + wm * 64;
  const int l15 = lane & 15, l16 = lane >> 4;

  f32x4 acc[4][4];
#pragma unroll
  for (int i = 0; i < 4; ++i)
#pragma unroll
    for (int j = 0; j < 4; ++j) acc[i][j] = (f32x4){0.f, 0.f, 0.f, 0.f};

#pragma unroll
  for (int kk = 0; kk < 4; ++kk) {
    const int ko = kk * 32 + l16 * 8;
    short8 a[4], b[4];
#pragma unroll
    for (int i = 0; i < 4; ++i) {
      int row = m0 + i * 16 + l15;
      if (row >= M) row = M - 1;
      a[i] = *(const short8*)(A + (size_t)row * 128 + ko);
    }
#pragma unroll
    for (int j = 0; j < 4; ++j) {
      int col = wn * 64 + j * 16 + l15;
      b[j] = *(const short8*)(W + (size_t)col * 128 + ko);
    }
#pragma unroll
    for (int i = 0; i < 4; ++i)
#pragma unroll
      for (int j = 0; j < 4; ++j)
        acc[i][j] = __builtin_amdgcn_mfma_f32_16x16x32_bf16(a[i], b[j], acc[i][j], 0, 0, 0);
  }

#pragma unroll
  for (int i = 0; i < 4; ++i)
#pragma unroll
    for (int r = 0; r < 4; ++r) {
      int row = m0 + i * 16 + l16 * 4 + r;
      if (row >= M) continue;
#pragma unroll
      for (int j = 0; j < 4; ++j) {
        int colw = wn * 64 + j * 16 + l15;
        float v = acc[i][j][r] + bias[colw];
        v = fmaxf(v, 0.f);
        outF[(size_t)row * 128 + colw] = v;
        outB[(size_t)row * 128 + colw] = f2bf(v);
      }
    }
}

// ---------------------------------------------------------------------------
// Layer GEMM: z = [h | u | v] @ Wbig[128][384]^T + bias_c  (fp32 out)
// A0 = h bf16 [M][128] (k 0..127), A1 = uv bf16 [M][256] (k 128..383).
// ---------------------------------------------------------------------------
__global__ __launch_bounds__(256) void layer_gemm(
    const ushort* __restrict__ A0, const ushort* __restrict__ A1,
    const ushort* __restrict__ W, const float* __restrict__ bias,
    float* __restrict__ outZ, int M) {
  const int t = threadIdx.x;
  const int lane = t & 63;
  const int w = t >> 6;
  const int wm = w >> 1, wn = w & 1;
  const int m0 = blockIdx.x * 128 + wm * 64;
  const int l15 = lane & 15, l16 = lane >> 4;

  f32x4 acc[4][4];
#pragma unroll
  for (int i = 0; i < 4; ++i)
#pragma unroll
    for (int j = 0; j < 4; ++j) acc[i][j] = (f32x4){0.f, 0.f, 0.f, 0.f};

#pragma unroll
  for (int kk = 0; kk < 12; ++kk) {
    const ushort* Ap = (kk < 4) ? A0 : A1;
    const int lda = (kk < 4) ? 128 : 256;
    const int koff = (kk < 4) ? kk * 32 : (kk - 4) * 32;
    const int ko = koff + l16 * 8;
    short8 a[4], b[4];
#pragma unroll
    for (int i = 0; i < 4; ++i) {
      int row = m0 + i * 16 + l15;
      if (row >= M) row = M - 1;
      a[i] = *(const short8*)(Ap + (size_t)row * lda + ko);
    }
#pragma unroll
    for (int j = 0; j < 4; ++j) {
      int col = wn * 64 + j * 16 + l15;
      b[j] = *(const short8*)(W + (size_t)col * 384 + kk * 32 + l16 * 8);
    }
#pragma unroll
    for (int i = 0; i < 4; ++i)
#pragma unroll
      for (int j = 0; j < 4; ++j)
        acc[i][j] = __builtin_amdgcn_mfma_f32_16x16x32_bf16(a[i], b[j], acc[i][j], 0, 0, 0);
  }

#pragma unroll
  for (int i = 0; i < 4; ++i)
#pragma unroll
    for (int r = 0; r < 4; ++r) {
      int row = m0 + i * 16 + l16 * 4 + r;
      if (row >= M) continue;
#pragma unroll
      for (int j = 0; j < 4; ++j) {
        int colw = wn * 64 + j * 16 + l15;
        outZ[(size_t)row * 128 + colw] = acc[i][j][r] + bias[colw];
      }
    }
}

// ---------------------------------------------------------------------------
// Weight precompute: Wbig[l][:, p*128:(p+1)*128] = Wcomb[l][:,p-part] @ Wp[l]
// fp32 product, bf16 store. One block per (l, p).
// ---------------------------------------------------------------------------
__global__ __launch_bounds__(256) void wpre_kernel(
    const float* __restrict__ Wcomb, const float* __restrict__ Wself,
    const float* __restrict__ Wfwd, const float* __restrict__ Wbwd,
    ushort* __restrict__ Wbig) {
  const int l = blockIdx.x / 3, p = blockIdx.x % 3;
  const float* Wc = Wcomb + (size_t)l * 128 * 384;
  const float* Wp = (p == 0 ? Wself : (p == 1 ? Wfwd : Wbwd)) + (size_t)l * 128 * 128;
  __shared__ float Bs[128][132];
  const int t = threadIdx.x;
  for (int i = t; i < 16384; i += 256) Bs[i >> 7][i & 127] = Wp[i];
  __syncthreads();
  const int r = t >> 1;
  const int c0 = (t & 1) * 64;
  float acc[64];
#pragma unroll
  for (int c = 0; c < 64; ++c) acc[c] = 0.f;
  for (int k = 0; k < 128; ++k) {
    float a = Wc[(size_t)r * 384 + p * 128 + k];
#pragma unroll
    for (int c4 = 0; c4 < 16; ++c4) {
      float4 b4 = *(const float4*)&Bs[k][c0 + c4 * 4];
      acc[c4 * 4 + 0] = fmaf(a, b4.x, acc[c4 * 4 + 0]);
      acc[c4 * 4 + 1] = fmaf(a, b4.y, acc[c4 * 4 + 1]);
      acc[c4 * 4 + 2] = fmaf(a, b4.z, acc[c4 * 4 + 2]);
      acc[c4 * 4 + 3] = fmaf(a, b4.w, acc[c4 * 4 + 3]);
    }
  }
  ushort* o = Wbig + (size_t)l * 128 * 384 + (size_t)r * 384 + p * 128 + c0;
#pragma unroll
  for (int c = 0; c < 64; ++c) o[c] = f2bf(acc[c]);
}

// bias_c[l][c] = bcomb[l][c] + sum_k Wcomb[l][c][k] * bself[l][k]
__global__ void bpre_kernel(const float* __restrict__ Wcomb, const float* __restrict__ bself,
                            const float* __restrict__ bcomb, float* __restrict__ biasc, int L) {
  int idx = blockIdx.x * 128 + threadIdx.x;
  if (idx >= L * 128) return;
  int l = idx >> 7;
  const float* Wc = Wcomb + (size_t)l * 128 * 384 + (size_t)(idx & 127) * 384;
  const float* bs = bself + (size_t)l * 128;
  float acc = bcomb[idx];
  for (int k = 0; k < 128; ++k) acc = fmaf(Wc[k], bs[k], acc);
  biasc[idx] = acc;
}

// fp32 -> bf16 (n4 float4 groups)
__global__ void f2b_kernel(const float* __restrict__ in, ushort* __restrict__ out, int n4) {
  int i = blockIdx.x * 256 + threadIdx.x;
  if (i < n4) {
    float4 v = ((const float4*)in)[i];
    ushort4 o;
    o.x = f2bf(v.x); o.y = f2bf(v.y); o.z = f2bf(v.z); o.w = f2bf(v.w);
    ((ushort4*)out)[i] = o;
  }
}

// ---------------------------------------------------------------------------
// scores[i] = dot(h_bf16[i,:], Wsc) + bsc  (one wave per node; used after embed)
// ---------------------------------------------------------------------------
__global__ __launch_bounds__(256) void score_kernel(
    const ushort* __restrict__ hb, const float* __restrict__ Wsc,
    const float* __restrict__ bsc, float* __restrict__ scores, int M) {
  int i = blockIdx.x * 4 + (threadIdx.x >> 6);
  if (i >= M) return;
  int lane = threadIdx.x & 63;
  unsigned v = *(const unsigned*)(hb + (size_t)i * 128 + lane * 2);
  float acc = bflo(v) * Wsc[2 * lane] + bfhi(v) * Wsc[2 * lane + 1];
#pragma unroll
  for (int off = 32; off >= 1; off >>= 1) acc += __shfl_xor(acc, off, 64);
  if (lane == 0) scores[i] = acc + bsc[0];
}

// ---------------------------------------------------------------------------
// CSR build: histogram -> scan -> scatter (counting sort by dst)
// ---------------------------------------------------------------------------
__global__ void hist_kernel(const int* __restrict__ dst, int* __restrict__ counts, int E) {
  int e = blockIdx.x * 256 + threadIdx.x;
  if (e < E) atomicAdd(&counts[dst[e]], 1);
}

__global__ __launch_bounds__(256) void scan1_kernel(
    const int* __restrict__ c, int* __restrict__ ex, int* __restrict__ partials, int n) {
  __shared__ int sd[256];
  int t = threadIdx.x, b = blockIdx.x;
  int base = b * 1024 + t * 4;
  int v0 = (base + 0 < n) ? c[base + 0] : 0;
  int v1 = (base + 1 < n) ? c[base + 1] : 0;
  int v2 = (base + 2 < n) ? c[base + 2] : 0;
  int v3 = (base + 3 < n) ? c[base + 3] : 0;
  int tot = v0 + v1 + v2 + v3;
  sd[t] = tot;
  __syncthreads();
  for (int off = 1; off < 256; off <<= 1) {
    int x = (t >= off) ? sd[t - off] : 0;
    __syncthreads();
    sd[t] += x;
    __syncthreads();
  }
  int p = sd[t] - tot;
  if (base + 0 < n) ex[base + 0] = p;
  if (base + 1 < n) ex[base + 1] = p + v0;
  if (base + 2 < n) ex[base + 2] = p + v0 + v1;
  if (base + 3 < n) ex[base + 3] = p + v0 + v1 + v2;
  if (t == 255) partials[b] = sd[255];
}

__global__ __launch_bounds__(256) void scan2_kernel(int* __restrict__ partials, int nb) {
  __shared__ int sd[256];
  int t = threadIdx.x;
  int v = (t < nb) ? partials[t] : 0;
  sd[t] = v;
  __syncthreads();
  for (int off = 1; off < 256; off <<= 1) {
    int x = (t >= off) ? sd[t - off] : 0;
    __syncthreads();
    sd[t] += x;
    __syncthreads();
  }
  if (t < nb) partials[t] = sd[t] - v;
}

__global__ void scan3_kernel(const int* __restrict__ ex, const int* __restrict__ partials,
                             int* __restrict__ indptr, int n, int E) {
  int i = blockIdx.x * 256 + threadIdx.x;
  if (i < n) indptr[i] = ex[i] + partials[i >> 10];
  if (i == 0) indptr[n] = E;
}

__global__ void scatter_kernel(const int* __restrict__ ei, int* __restrict__ cursor,
                               int* __restrict__ ssrc, int E) {
  int e = blockIdx.x * 256 + threadIdx.x;
  if (e >= E) return;
  int s = ei[e];
  int d = ei[E + e];
  int pos = atomicAdd(&cursor[d], 1);
  ssrc[pos] = s;
}

// ---------------------------------------------------------------------------
// Edge aggregation in h-space: u[i] = sum al*h[s], v[i] = sum h[s] - u[i].
// 1 wave/node; two 32-lane halves process even/odd edges concurrently;
// each half reads the full 256B bf16 row (uint2/lane, 4 dims).
// Cross-half reduce via shfl_xor(32). Writes uv[N][256] bf16 = [u | v].
// ---------------------------------------------------------------------------
__global__ __launch_bounds__(256) void aggr_kernel(
    const int* __restrict__ indptr, const int* __restrict__ ssrc,
    const float* __restrict__ scores, const ushort* __restrict__ hb,
    ushort* __restrict__ uv, int Nn) {
  int node = blockIdx.x * 4 + (threadIdx.x >> 6);
  if (node >= Nn) return;
  int lane = threadIdx.x & 63;
  int half = lane >> 5;
  int hl = lane & 31;
  int beg = indptr[node], end = indptr[node + 1];
  float si = scores[node];
  float u0 = 0.f, u1 = 0.f, u2 = 0.f, u3 = 0.f;
  float s0 = 0.f, s1 = 0.f, s2 = 0.f, s3 = 0.f;
  for (int e = beg + half; e < end; e += 2) {
    int s = ssrc[e];
    float al = 1.f / (1.f + __expf(si - scores[s]));  // sigmoid(scores[s]-si)
    uint2 v = *(const uint2*)(hb + (size_t)s * 128 + hl * 4);
    float f0 = bflo(v.x), f1 = bfhi(v.x), f2 = bflo(v.y), f3 = bfhi(v.y);
    u0 = fmaf(al, f0, u0); u1 = fmaf(al, f1, u1);
    u2 = fmaf(al, f2, u2); u3 = fmaf(al, f3, u3);
    s0 += f0; s1 += f1; s2 += f2; s3 += f3;
  }
  u0 += __shfl_xor(u0, 32, 64); u1 += __shfl_xor(u1, 32, 64);
  u2 += __shfl_xor(u2, 32, 64); u3 += __shfl_xor(u3, 32, 64);
  s0 += __shfl_xor(s0, 32, 64); s1 += __shfl_xor(s1, 32, 64);
  s2 += __shfl_xor(s2, 32, 64); s3 += __shfl_xor(s3, 32, 64);
  float w0, w1, w2, w3;
  if (half == 0) { w0 = u0; w1 = u1; w2 = u2; w3 = u3; }
  else { w0 = s0 - u0; w1 = s1 - u1; w2 = s2 - u2; w3 = s3 - u3; }
  ushort4 o;
  o.x = f2bf(w0); o.y = f2bf(w1); o.z = f2bf(w2); o.w = f2bf(w3);
  *(ushort4*)(uv + (size_t)node * 256 + half * 128 + hl * 4) = o;
}

// ---------------------------------------------------------------------------
// LayerNorm + ReLU + residual; writes h (fp32) and hb16; optionally computes
// next-layer scores from the NEW h (Wsc/bsc/scores null-able).
// ---------------------------------------------------------------------------
__global__ __launch_bounds__(256) void ln_kernel(
    const float* __restrict__ z, const float* __restrict__ gamma,
    const float* __restrict__ beta, const float* __restrict__ Wsc,
    const float* __restrict__ bsc, float* __restrict__ h,
    ushort* __restrict__ hb, float* __restrict__ scores, int M) {
  int wid = threadIdx.x >> 6, lane = threadIdx.x & 63;
  int i = blockIdx.x * 4 + wid;
  if (i >= M) return;
  float z0 = z[(size_t)i * 128 + lane];
  float z1 = z[(size_t)i * 128 + 64 + lane];
  float s1 = z0 + z1;
  float s2 = z0 * z0 + z1 * z1;
#pragma unroll
  for (int off = 32; off >= 1; off >>= 1) {
    s1 += __shfl_xor(s1, off, 64);
    s2 += __shfl_xor(s2, off, 64);
  }
  float mu = s1 * (1.f / 128.f);
  float var = s2 * (1.f / 128.f) - mu * mu;
  float rs = rsqrtf(var + EPS);
  float o0 = (z0 - mu) * rs * gamma[lane] + beta[lane];
  float o1 = (z1 - mu) * rs * gamma[64 + lane] + beta[64 + lane];
  o0 = fmaxf(o0, 0.f);
  o1 = fmaxf(o1, 0.f);
  size_t p0 = (size_t)i * 128 + lane;
  size_t p1 = p0 + 64;
  float r0 = o0 + h[p0];
  float r1 = o1 + h[p1];
  h[p0] = r0;
  h[p1] = r1;
  hb[p0] = f2bf(r0);
  hb[p1] = f2bf(r1);
  if (Wsc) {
    float acc = r0 * Wsc[lane] + r1 * Wsc[64 + lane];
#pragma unroll
    for (int off = 32; off >= 1; off >>= 1) acc += __shfl_xor(acc, off, 64);
    if (lane == 0) scores[i] = acc + bsc[0];
  }
}

// ---------------------------------------------------------------------------
// Global mean pool (batch sorted); counts via binary search.
// ---------------------------------------------------------------------------
__global__ __launch_bounds__(128) void pool_accum_kernel(
    const float* __restrict__ h, const int* __restrict__ batch,
    float* __restrict__ sums, int M) {
  int i0 = blockIdx.x * 128;
  int d = threadIdx.x;
  float acc = 0.f;
  int cur = -1;
  for (int ii = 0; ii < 128; ++ii) {
    int i = i0 + ii;
    if (i >= M) break;
    int g = batch[i];
    if (g != cur) {
      if (cur >= 0) atomicAdd(&sums[cur * 128 + d], acc);
      acc = 0.f;
      cur = g;
    }
    acc += h[(size_t)i * 128 + d];
  }
  if (cur >= 0) atomicAdd(&sums[cur * 128 + d], acc);
}

__global__ void group_count_kernel(const int* __restrict__ batch, int* __restrict__ cnt,
                                   int M, int G) {
  int g = blockIdx.x * 64 + threadIdx.x;
  if (g >= G) return;
  int lo = 0, hi = M;
  while (lo < hi) { int mid = (lo + hi) >> 1; if (batch[mid] < g) lo = mid + 1; else hi = mid; }
  int b0 = lo;
  lo = 0; hi = M;
  while (lo < hi) { int mid = (lo + hi) >> 1; if (batch[mid] < g + 1) lo = mid + 1; else hi = mid; }
  cnt[g] = lo - b0;
}

__global__ void finalize_kernel(const float* __restrict__ sums, const int* __restrict__ cnt,
                                float* __restrict__ out, int G) {
  int idx = blockIdx.x * 256 + threadIdx.x;
  if (idx < G * 128) {
    int g = idx >> 7;
    int c = cnt[g];
    float cf = (float)(c > 0 ? c : 1);
    out[idx] = sums[idx] / cf;
  }
}

// ---------------------------------------------------------------------------
extern "C" void kernel_launch(void* const* d_in, const int* in_sizes, int n_in,
                              void* d_out, int out_size, void* d_ws, size_t ws_size,
                              hipStream_t stream) {
  const float* x      = (const float*)d_in[0];
  const int*   ei     = (const int*)d_in[1];
  const int*   batch  = (const int*)d_in[2];
  const float* Wemb   = (const float*)d_in[3];
  const float* bemb   = (const float*)d_in[4];
  const float* Wscore = (const float*)d_in[5];
  const float* bscore = (const float*)d_in[6];
  const float* Wfwd   = (const float*)d_in[7];
  const float* Wbwd   = (const float*)d_in[8];
  const float* Wself  = (const float*)d_in[9];
  const float* bself  = (const float*)d_in[10];
  const float* Wcomb  = (const float*)d_in[11];
  const float* bcomb  = (const float*)d_in[12];
  const float* gamma  = (const float*)d_in[13];
  const float* beta   = (const float*)d_in[14];

  const int N = in_sizes[0] / 128;
  const int E = in_sizes[1] / 2;
  const int L = in_sizes[5] / 128;
  const int G = out_size / 128;
  float* out = (float*)d_out;

  char* p = (char*)d_ws;
  auto alloc = [&](size_t bytes) -> char* {
    char* r = p;
    p += (bytes + 255) & ~(size_t)255;
    return r;
  };
  float*  h      = (float*)alloc((size_t)N * 128 * 4);
  ushort* hb16   = (ushort*)alloc((size_t)N * 128 * 2);
  ushort* xb16   = (ushort*)alloc((size_t)N * 128 * 2);
  ushort* uv     = (ushort*)alloc((size_t)N * 256 * 2);   // [u | v] bf16
  float*  z      = (float*)alloc((size_t)N * 128 * 4);
  float*  scores = (float*)alloc((size_t)N * 4);
  ushort* Wemb_b = (ushort*)alloc(16384 * 2);
  ushort* Wbig   = (ushort*)alloc((size_t)L * 128 * 384 * 2);
  float*  biasc  = (float*)alloc((size_t)L * 128 * 4);
  int* counts    = (int*)alloc((size_t)N * 4);
  int* ex        = (int*)alloc((size_t)N * 4);
  int* partials  = (int*)alloc(1024);
  int* indptr    = (int*)alloc((size_t)(N + 1) * 4);
  int* cursor    = (int*)alloc((size_t)N * 4);
  int* ssrc      = (int*)alloc((size_t)E * 4);
  float* sums    = (float*)alloc((size_t)G * 128 * 4);
  int* cnt       = (int*)alloc((size_t)G * 4);

  const int gb = (N + 127) / 128;

  // 0. precompute: conversions + combined weights (fp32 products -> bf16)
  f2b_kernel<<<(N * 32 + 255) / 256, 256, 0, stream>>>(x, xb16, N * 32);
  f2b_kernel<<<16, 256, 0, stream>>>(Wemb, Wemb_b, 4096);
  wpre_kernel<<<3 * L, 256, 0, stream>>>(Wcomb, Wself, Wfwd, Wbwd, Wbig);
  bpre_kernel<<<L, 128, 0, stream>>>(Wcomb, bself, bcomb, biasc, L);

  // 1. embedding: h = relu(x @ Wemb^T + bemb) -> h fp32 + hb16
  embed_gemm<<<gb, 256, 0, stream>>>(xb16, Wemb_b, bemb, h, hb16, N);
  score_kernel<<<(N + 3) / 4, 256, 0, stream>>>(hb16, Wscore, bscore, scores, N);

  // 2. CSR build
  hipMemsetAsync(counts, 0, (size_t)N * 4, stream);
  hist_kernel<<<(E + 255) / 256, 256, 0, stream>>>(ei + E, counts, E);
  int nb = (N + 1023) / 1024;
  scan1_kernel<<<nb, 256, 0, stream>>>(counts, ex, partials, N);
  scan2_kernel<<<1, 256, 0, stream>>>(partials, nb);
  scan3_kernel<<<(N + 255) / 256, 256, 0, stream>>>(ex, partials, indptr, N, E);
  hipMemcpyAsync(cursor, indptr, (size_t)N * 4, hipMemcpyDeviceToDevice, stream);
  scatter_kernel<<<(E + 255) / 256, 256, 0, stream>>>(ei, cursor, ssrc, E);

  // 3. layers
  for (int l = 0; l < L; ++l) {
    aggr_kernel<<<(N + 3) / 4, 256, 0, stream>>>(indptr, ssrc, scores, hb16, uv, N);
    layer_gemm<<<gb, 256, 0, stream>>>(hb16, uv, Wbig + (size_t)l * 128 * 384,
                                       biasc + (size_t)l * 128, z, N);
    const bool last = (l == L - 1);
    ln_kernel<<<(N + 3) / 4, 256, 0, stream>>>(
        z, gamma + (size_t)l * 128, beta + (size_t)l * 128,
        last ? nullptr : Wscore + (size_t)(l + 1) * 128,
        last ? nullptr : bscore + (l + 1), h, hb16, scores, N);
  }

  // 4. global mean pool
  hipMemsetAsync(sums, 0, (size_t)G * 128 * 4, stream);
  group_count_kernel<<<(G + 63) / 64, 64, 0, stream>>>(batch, cnt, N, G);
  pool_accum_kernel<<<(N + 127) / 128, 128, 0, stream>>>(h, batch, sums, N);
  finalize_kernel<<<(G * 128 + 255) / 256, 256, 0, stream>>>(sums, cnt, out, G);
}

// Round 5
// 549.212 us; speedup vs baseline: 2.6926x; 1.0174x over previous
//
#include <hip/hip_runtime.h>
#include <math.h>

#define EPS 1e-5f

typedef __attribute__((ext_vector_type(8))) short short8;
typedef __attribute__((ext_vector_type(4))) float f32x4;

__device__ __forceinline__ float bflo(unsigned u) {
  union { unsigned i; float f; } c; c.i = u << 16; return c.f;
}
__device__ __forceinline__ float bfhi(unsigned u) {
  union { unsigned i; float f; } c; c.i = u & 0xFFFF0000u; return c.f;
}
__device__ __forceinline__ unsigned short f2bf(float f) {
  union { float f; unsigned i; } c; c.f = f;
  unsigned r = c.i + 0x7FFF + ((c.i >> 16) & 1);
  return (unsigned short)(r >> 16);
}

// ---------------------------------------------------------------------------
// Fused GEMM + epilogue.
// MODE 0 (embed): h = relu(x_f32 @ W^T + bias); writes h fp32 + hb bf16;
//                 optional scores = h @ Wsc + bsc.
// MODE 1 (layer): z = [hb | uv] @ W^T + bias (K=384); LayerNorm(gamma,beta);
//                 relu; += h residual; writes h fp32 + hb bf16; optional score.
// 256 thr = 4 waves (2 wm x 2 wn), tile 128x128, per-wave 64x64, 16x16x32 bf16.
// Row stats cross-wave reduction via LDS ([128][2] planes).
// ---------------------------------------------------------------------------
template <int MODE, bool SCORE>
__global__ __launch_bounds__(256) void fused_gemm(
    const float* __restrict__ Axf,    // MODE 0: x fp32 [M][128]
    const ushort* __restrict__ A0,    // MODE 1: hb [M][128] bf16
    const ushort* __restrict__ A1,    // MODE 1: uv [M][256] bf16
    const ushort* __restrict__ W,     // [128][K] bf16
    const float* __restrict__ bias,   // [128]
    const float* __restrict__ gamma,  // MODE 1
    const float* __restrict__ beta,   // MODE 1
    const float* __restrict__ Wsc,    // SCORE
    const float* __restrict__ bsc,    // SCORE
    float* __restrict__ h,            // state fp32 (MODE1: read residual + write)
    ushort* __restrict__ hb,          // state bf16
    float* __restrict__ scores, int M) {
  constexpr int KT = (MODE == 0) ? 4 : 12;
  constexpr int K = KT * 32;
  const int t = threadIdx.x;
  const int lane = t & 63;
  const int w = t >> 6;
  const int wm = w >> 1, wn = w & 1;
  const int m0 = blockIdx.x * 128 + wm * 64;
  const int l15 = lane & 15, l16 = lane >> 4;

  __shared__ float lds1[128][2];
  __shared__ float lds2[128][2];
  __shared__ float lds3[128][2];

  f32x4 acc[4][4];
#pragma unroll
  for (int i = 0; i < 4; ++i)
#pragma unroll
    for (int j = 0; j < 4; ++j) acc[i][j] = (f32x4){0.f, 0.f, 0.f, 0.f};

#pragma unroll
  for (int kk = 0; kk < KT; ++kk) {
    short8 a[4], b[4];
#pragma unroll
    for (int i = 0; i < 4; ++i) {
      int row = m0 + i * 16 + l15;
      if (row >= M) row = M - 1;
      if (MODE == 0) {
        const float* xr = Axf + (size_t)row * 128 + kk * 32 + l16 * 8;
        float4 f0 = *(const float4*)xr;
        float4 f1 = *(const float4*)(xr + 4);
        a[i][0] = (short)f2bf(f0.x); a[i][1] = (short)f2bf(f0.y);
        a[i][2] = (short)f2bf(f0.z); a[i][3] = (short)f2bf(f0.w);
        a[i][4] = (short)f2bf(f1.x); a[i][5] = (short)f2bf(f1.y);
        a[i][6] = (short)f2bf(f1.z); a[i][7] = (short)f2bf(f1.w);
      } else {
        if (kk < 4) {
          a[i] = *(const short8*)(A0 + (size_t)row * 128 + kk * 32 + l16 * 8);
        } else {
          a[i] = *(const short8*)(A1 + (size_t)row * 256 + (kk - 4) * 32 + l16 * 8);
        }
      }
    }
#pragma unroll
    for (int j = 0; j < 4; ++j) {
      int col = wn * 64 + j * 16 + l15;
      b[j] = *(const short8*)(W + (size_t)col * K + kk * 32 + l16 * 8);
    }
#pragma unroll
    for (int i = 0; i < 4; ++i)
#pragma unroll
      for (int j = 0; j < 4; ++j)
        acc[i][j] = __builtin_amdgcn_mfma_f32_16x16x32_bf16(a[i], b[j], acc[i][j], 0, 0, 0);
  }

  if (MODE == 0) {
    // relu epilogue + optional score
#pragma unroll
    for (int i = 0; i < 4; ++i)
#pragma unroll
      for (int r = 0; r < 4; ++r) {
        int row = m0 + i * 16 + l16 * 4 + r;
        bool valid = row < M;
        float psc = 0.f;
#pragma unroll
        for (int j = 0; j < 4; ++j) {
          int colw = wn * 64 + j * 16 + l15;
          float v = acc[i][j][r] + bias[colw];
          v = fmaxf(v, 0.f);
          if (valid) {
            h[(size_t)row * 128 + colw] = v;
            hb[(size_t)row * 128 + colw] = f2bf(v);
          }
          if (SCORE) psc += v * Wsc[colw];
        }
        if (SCORE) {
#pragma unroll
          for (int mm = 1; mm <= 8; mm <<= 1) psc += __shfl_xor(psc, mm, 64);
          if (l15 == 0) lds3[wm * 64 + i * 16 + l16 * 4 + r][wn] = psc;
        }
      }
    if (SCORE) {
      __syncthreads();
      if (wn == 0 && l15 == 0) {
#pragma unroll
        for (int i = 0; i < 4; ++i)
#pragma unroll
          for (int r = 0; r < 4; ++r) {
            int rl = wm * 64 + i * 16 + l16 * 4 + r;
            int row = blockIdx.x * 128 + rl;
            if (row < M) scores[row] = lds3[rl][0] + lds3[rl][1] + bsc[0];
          }
      }
    }
  } else {
    // bias + LN stats (pass 1)
#pragma unroll
    for (int i = 0; i < 4; ++i)
#pragma unroll
      for (int r = 0; r < 4; ++r) {
        float p1 = 0.f, p2 = 0.f;
#pragma unroll
        for (int j = 0; j < 4; ++j) {
          int colw = wn * 64 + j * 16 + l15;
          float v = acc[i][j][r] + bias[colw];
          acc[i][j][r] = v;
          p1 += v;
          p2 += v * v;
        }
#pragma unroll
        for (int mm = 1; mm <= 8; mm <<= 1) {
          p1 += __shfl_xor(p1, mm, 64);
          p2 += __shfl_xor(p2, mm, 64);
        }
        if (l15 == 0) {
          int rl = wm * 64 + i * 16 + l16 * 4 + r;
          lds1[rl][wn] = p1;
          lds2[rl][wn] = p2;
        }
      }
    __syncthreads();
    // pass 2: normalize + relu + residual + store (+ score partial)
#pragma unroll
    for (int i = 0; i < 4; ++i)
#pragma unroll
      for (int r = 0; r < 4; ++r) {
        int rl = wm * 64 + i * 16 + l16 * 4 + r;
        int row = blockIdx.x * 128 + rl;
        bool valid = row < M;
        float s1 = lds1[rl][0] + lds1[rl][1];
        float s2 = lds2[rl][0] + lds2[rl][1];
        float mu = s1 * (1.f / 128.f);
        float var = s2 * (1.f / 128.f) - mu * mu;
        float rs = rsqrtf(var + EPS);
        float psc = 0.f;
#pragma unroll
        for (int j = 0; j < 4; ++j) {
          int colw = wn * 64 + j * 16 + l15;
          float v = acc[i][j][r];
          float o = (v - mu) * rs * gamma[colw] + beta[colw];
          o = fmaxf(o, 0.f);
          float res = o;
          if (valid) {
            res = o + h[(size_t)row * 128 + colw];
            h[(size_t)row * 128 + colw] = res;
            hb[(size_t)row * 128 + colw] = f2bf(res);
          }
          if (SCORE) psc += res * Wsc[colw];
        }
        if (SCORE) {
#pragma unroll
          for (int mm = 1; mm <= 8; mm <<= 1) psc += __shfl_xor(psc, mm, 64);
          if (l15 == 0) lds3[rl][wn] = psc;
        }
      }
    if (SCORE) {
      __syncthreads();
      if (wn == 0 && l15 == 0) {
#pragma unroll
        for (int i = 0; i < 4; ++i)
#pragma unroll
          for (int r = 0; r < 4; ++r) {
            int rl = wm * 64 + i * 16 + l16 * 4 + r;
            int row = blockIdx.x * 128 + rl;
            if (row < M) scores[row] = lds3[rl][0] + lds3[rl][1] + bsc[0];
          }
      }
    }
  }
}

// ---------------------------------------------------------------------------
// Weight precompute: Wbig[l][:, p*128:(p+1)*128] = Wcomb[l][:,p-part] @ Wp[l]
// ---------------------------------------------------------------------------
__global__ __launch_bounds__(256) void wpre_kernel(
    const float* __restrict__ Wcomb, const float* __restrict__ Wself,
    const float* __restrict__ Wfwd, const float* __restrict__ Wbwd,
    ushort* __restrict__ Wbig) {
  const int l = blockIdx.x / 3, p = blockIdx.x % 3;
  const float* Wc = Wcomb + (size_t)l * 128 * 384;
  const float* Wp = (p == 0 ? Wself : (p == 1 ? Wfwd : Wbwd)) + (size_t)l * 128 * 128;
  __shared__ float Bs[128][132];
  const int t = threadIdx.x;
  for (int i = t; i < 16384; i += 256) Bs[i >> 7][i & 127] = Wp[i];
  __syncthreads();
  const int r = t >> 1;
  const int c0 = (t & 1) * 64;
  float acc[64];
#pragma unroll
  for (int c = 0; c < 64; ++c) acc[c] = 0.f;
  for (int k = 0; k < 128; ++k) {
    float a = Wc[(size_t)r * 384 + p * 128 + k];
#pragma unroll
    for (int c4 = 0; c4 < 16; ++c4) {
      float4 b4 = *(const float4*)&Bs[k][c0 + c4 * 4];
      acc[c4 * 4 + 0] = fmaf(a, b4.x, acc[c4 * 4 + 0]);
      acc[c4 * 4 + 1] = fmaf(a, b4.y, acc[c4 * 4 + 1]);
      acc[c4 * 4 + 2] = fmaf(a, b4.z, acc[c4 * 4 + 2]);
      acc[c4 * 4 + 3] = fmaf(a, b4.w, acc[c4 * 4 + 3]);
    }
  }
  ushort* o = Wbig + (size_t)l * 128 * 384 + (size_t)r * 384 + p * 128 + c0;
#pragma unroll
  for (int c = 0; c < 64; ++c) o[c] = f2bf(acc[c]);
}

// bias_c[l][c] = bcomb[l][c] + sum_k Wcomb[l][c][k] * bself[l][k]
__global__ void bpre_kernel(const float* __restrict__ Wcomb, const float* __restrict__ bself,
                            const float* __restrict__ bcomb, float* __restrict__ biasc, int L) {
  int idx = blockIdx.x * 128 + threadIdx.x;
  if (idx >= L * 128) return;
  int l = idx >> 7;
  const float* Wc = Wcomb + (size_t)l * 128 * 384 + (size_t)(idx & 127) * 384;
  const float* bs = bself + (size_t)l * 128;
  float acc = bcomb[idx];
  for (int k = 0; k < 128; ++k) acc = fmaf(Wc[k], bs[k], acc);
  biasc[idx] = acc;
}

// fp32 -> bf16 (n4 float4 groups)
__global__ void f2b_kernel(const float* __restrict__ in, ushort* __restrict__ out, int n4) {
  int i = blockIdx.x * 256 + threadIdx.x;
  if (i < n4) {
    float4 v = ((const float4*)in)[i];
    ushort4 o;
    o.x = f2bf(v.x); o.y = f2bf(v.y); o.z = f2bf(v.z); o.w = f2bf(v.w);
    ((ushort4*)out)[i] = o;
  }
}

// ---------------------------------------------------------------------------
// CSR build: histogram -> scan -> scatter (counting sort by dst)
// ---------------------------------------------------------------------------
__global__ void hist_kernel(const int* __restrict__ dst, int* __restrict__ counts, int E) {
  int e = blockIdx.x * 256 + threadIdx.x;
  if (e < E) atomicAdd(&counts[dst[e]], 1);
}

__global__ __launch_bounds__(256) void scan1_kernel(
    const int* __restrict__ c, int* __restrict__ ex, int* __restrict__ partials, int n) {
  __shared__ int sd[256];
  int t = threadIdx.x, b = blockIdx.x;
  int base = b * 1024 + t * 4;
  int v0 = (base + 0 < n) ? c[base + 0] : 0;
  int v1 = (base + 1 < n) ? c[base + 1] : 0;
  int v2 = (base + 2 < n) ? c[base + 2] : 0;
  int v3 = (base + 3 < n) ? c[base + 3] : 0;
  int tot = v0 + v1 + v2 + v3;
  sd[t] = tot;
  __syncthreads();
  for (int off = 1; off < 256; off <<= 1) {
    int x = (t >= off) ? sd[t - off] : 0;
    __syncthreads();
    sd[t] += x;
    __syncthreads();
  }
  int p = sd[t] - tot;
  if (base + 0 < n) ex[base + 0] = p;
  if (base + 1 < n) ex[base + 1] = p + v0;
  if (base + 2 < n) ex[base + 2] = p + v0 + v1;
  if (base + 3 < n) ex[base + 3] = p + v0 + v1 + v2;
  if (t == 255) partials[b] = sd[255];
}

__global__ __launch_bounds__(256) void scan2_kernel(int* __restrict__ partials, int nb) {
  __shared__ int sd[256];
  int t = threadIdx.x;
  int v = (t < nb) ? partials[t] : 0;
  sd[t] = v;
  __syncthreads();
  for (int off = 1; off < 256; off <<= 1) {
    int x = (t >= off) ? sd[t - off] : 0;
    __syncthreads();
    sd[t] += x;
    __syncthreads();
  }
  if (t < nb) partials[t] = sd[t] - v;
}

__global__ void scan3_kernel(const int* __restrict__ ex, const int* __restrict__ partials,
                             int* __restrict__ indptr, int n, int E) {
  int i = blockIdx.x * 256 + threadIdx.x;
  if (i < n) indptr[i] = ex[i] + partials[i >> 10];
  if (i == 0) indptr[n] = E;
}

__global__ void scatter_kernel(const int* __restrict__ ei, int* __restrict__ cursor,
                               int* __restrict__ ssrc, int E) {
  int e = blockIdx.x * 256 + threadIdx.x;
  if (e >= E) return;
  int s = ei[e];
  int d = ei[E + e];
  int pos = atomicAdd(&cursor[d], 1);
  ssrc[pos] = s;
}

// ---------------------------------------------------------------------------
// Edge aggregation: 1 wave/node. Lane-parallel prefetch of up to 64 edges'
// (src, alpha); inner loop broadcasts (s,alpha) and streams independent
// 256B row loads. u = sum al*h[s]; v = sum h[s] - u. uv[N][256] bf16.
// ---------------------------------------------------------------------------
__global__ __launch_bounds__(256) void aggr_kernel(
    const int* __restrict__ indptr, const int* __restrict__ ssrc,
    const float* __restrict__ scores, const ushort* __restrict__ hb,
    ushort* __restrict__ uv, int Nn) {
  int node = blockIdx.x * 4 + (threadIdx.x >> 6);
  if (node >= Nn) return;
  int lane = threadIdx.x & 63;
  int beg = indptr[node], end = indptr[node + 1];
  float si = scores[node];
  float u0 = 0.f, u1 = 0.f, t0 = 0.f, t1 = 0.f;
  for (int ebase = beg; ebase < end; ebase += 64) {
    int cnt = min(64, end - ebase);
    int sv = 0;
    float al = 0.f;
    if (lane < cnt) {
      sv = ssrc[ebase + lane];
      al = 1.f / (1.f + __expf(si - scores[sv]));  // sigmoid(scores[s]-si)
    }
    for (int e = 0; e < cnt; ++e) {
      int s_e = __shfl(sv, e, 64);
      float a_e = __shfl(al, e, 64);
      unsigned vv = *(const unsigned*)(hb + (size_t)s_e * 128 + lane * 2);
      float f0 = bflo(vv), f1 = bfhi(vv);
      u0 = fmaf(a_e, f0, u0);
      u1 = fmaf(a_e, f1, u1);
      t0 += f0;
      t1 += f1;
    }
  }
  unsigned pu = (unsigned)f2bf(u0) | ((unsigned)f2bf(u1) << 16);
  unsigned pv = (unsigned)f2bf(t0 - u0) | ((unsigned)f2bf(t1 - u1) << 16);
  *(unsigned*)(uv + (size_t)node * 256 + lane * 2) = pu;
  *(unsigned*)(uv + (size_t)node * 256 + 128 + lane * 2) = pv;
}

// ---------------------------------------------------------------------------
// Global mean pool (batch sorted); counts via in-kernel binary search.
// ---------------------------------------------------------------------------
__global__ __launch_bounds__(128) void pool_accum_kernel(
    const float* __restrict__ h, const int* __restrict__ batch,
    float* __restrict__ sums, int M) {
  int i0 = blockIdx.x * 128;
  int d = threadIdx.x;
  float acc = 0.f;
  int cur = -1;
  for (int ii = 0; ii < 128; ++ii) {
    int i = i0 + ii;
    if (i >= M) break;
    int g = batch[i];
    if (g != cur) {
      if (cur >= 0) atomicAdd(&sums[cur * 128 + d], acc);
      acc = 0.f;
      cur = g;
    }
    acc += h[(size_t)i * 128 + d];
  }
  if (cur >= 0) atomicAdd(&sums[cur * 128 + d], acc);
}

__global__ void finalize_kernel(const float* __restrict__ sums, const int* __restrict__ batch,
                                float* __restrict__ out, int M, int G) {
  int idx = blockIdx.x * 256 + threadIdx.x;
  if (idx >= G * 128) return;
  int g = idx >> 7;
  int lo = 0, hi = M;
  while (lo < hi) { int mid = (lo + hi) >> 1; if (batch[mid] < g) lo = mid + 1; else hi = mid; }
  int b0 = lo;
  hi = M;
  while (lo < hi) { int mid = (lo + hi) >> 1; if (batch[mid] <= g) lo = mid + 1; else hi = mid; }
  int c = lo - b0;
  out[idx] = sums[idx] / (float)(c > 0 ? c : 1);
}

// ---------------------------------------------------------------------------
extern "C" void kernel_launch(void* const* d_in, const int* in_sizes, int n_in,
                              void* d_out, int out_size, void* d_ws, size_t ws_size,
                              hipStream_t stream) {
  const float* x      = (const float*)d_in[0];
  const int*   ei     = (const int*)d_in[1];
  const int*   batch  = (const int*)d_in[2];
  const float* Wemb   = (const float*)d_in[3];
  const float* bemb   = (const float*)d_in[4];
  const float* Wscore = (const float*)d_in[5];
  const float* bscore = (const float*)d_in[6];
  const float* Wfwd   = (const float*)d_in[7];
  const float* Wbwd   = (const float*)d_in[8];
  const float* Wself  = (const float*)d_in[9];
  const float* bself  = (const float*)d_in[10];
  const float* Wcomb  = (const float*)d_in[11];
  const float* bcomb  = (const float*)d_in[12];
  const float* gamma  = (const float*)d_in[13];
  const float* beta   = (const float*)d_in[14];

  const int N = in_sizes[0] / 128;
  const int E = in_sizes[1] / 2;
  const int L = in_sizes[5] / 128;
  const int G = out_size / 128;
  float* out = (float*)d_out;

  char* p = (char*)d_ws;
  auto alloc = [&](size_t bytes) -> char* {
    char* r = p;
    p += (bytes + 255) & ~(size_t)255;
    return r;
  };
  float*  h      = (float*)alloc((size_t)N * 128 * 4);
  ushort* hb16   = (ushort*)alloc((size_t)N * 128 * 2);
  ushort* uv     = (ushort*)alloc((size_t)N * 256 * 2);   // [u | v] bf16
  float*  scores = (float*)alloc((size_t)N * 4);
  ushort* Wemb_b = (ushort*)alloc(16384 * 2);
  ushort* Wbig   = (ushort*)alloc((size_t)L * 128 * 384 * 2);
  float*  biasc  = (float*)alloc((size_t)L * 128 * 4);
  int* counts    = (int*)alloc((size_t)N * 4);
  int* ex        = (int*)alloc((size_t)N * 4);
  int* partials  = (int*)alloc(1024);
  int* indptr    = (int*)alloc((size_t)(N + 1) * 4);
  int* cursor    = (int*)alloc((size_t)N * 4);
  int* ssrc      = (int*)alloc((size_t)E * 4);
  float* sums    = (float*)alloc((size_t)G * 128 * 4);

  const int gb = (N + 127) / 128;

  // 0. precompute: weight conversions + combined weights
  f2b_kernel<<<16, 256, 0, stream>>>(Wemb, Wemb_b, 4096);
  wpre_kernel<<<3 * L, 256, 0, stream>>>(Wcomb, Wself, Wfwd, Wbwd, Wbig);
  bpre_kernel<<<L, 128, 0, stream>>>(Wcomb, bself, bcomb, biasc, L);

  // 1. CSR build (edges constant within a call)
  hipMemsetAsync(counts, 0, (size_t)N * 4, stream);
  hist_kernel<<<(E + 255) / 256, 256, 0, stream>>>(ei + E, counts, E);
  int nb = (N + 1023) / 1024;
  scan1_kernel<<<nb, 256, 0, stream>>>(counts, ex, partials, N);
  scan2_kernel<<<1, 256, 0, stream>>>(partials, nb);
  scan3_kernel<<<(N + 255) / 256, 256, 0, stream>>>(ex, partials, indptr, N, E);
  hipMemcpyAsync(cursor, indptr, (size_t)N * 4, hipMemcpyDeviceToDevice, stream);
  scatter_kernel<<<(E + 255) / 256, 256, 0, stream>>>(ei, cursor, ssrc, E);

  // 2. embedding: h = relu(x @ Wemb^T + bemb), fused layer-0 scores
  fused_gemm<0, true><<<gb, 256, 0, stream>>>(
      x, nullptr, nullptr, Wemb_b, bemb, nullptr, nullptr,
      Wscore, bscore, h, hb16, scores, N);

  // 3. layers: aggr -> fused GEMM+LN+residual(+next scores)
  for (int l = 0; l < L; ++l) {
    aggr_kernel<<<(N + 3) / 4, 256, 0, stream>>>(indptr, ssrc, scores, hb16, uv, N);
    if (l < L - 1) {
      fused_gemm<1, true><<<gb, 256, 0, stream>>>(
          nullptr, hb16, uv, Wbig + (size_t)l * 128 * 384, biasc + (size_t)l * 128,
          gamma + (size_t)l * 128, beta + (size_t)l * 128,
          Wscore + (size_t)(l + 1) * 128, bscore + (l + 1), h, hb16, scores, N);
    } else {
      fused_gemm<1, false><<<gb, 256, 0, stream>>>(
          nullptr, hb16, uv, Wbig + (size_t)l * 128 * 384, biasc + (size_t)l * 128,
          gamma + (size_t)l * 128, beta + (size_t)l * 128,
          nullptr, nullptr, h, hb16, scores, N);
    }
  }

  // 4. global mean pool
  hipMemsetAsync(sums, 0, (size_t)G * 128 * 4, stream);
  pool_accum_kernel<<<(N + 127) / 128, 128, 0, stream>>>(h, batch, sums, N);
  finalize_kernel<<<(G * 128 + 255) / 256, 256, 0, stream>>>(sums, batch, out, N, G);
}